// Round 2
// baseline (1445.885 us; speedup 1.0000x reference)
//
#include <hip/hip_runtime.h>

typedef unsigned short u16;
typedef unsigned int u32;
typedef short short8 __attribute__((ext_vector_type(8)));
typedef float float4v __attribute__((ext_vector_type(4)));

#define L_SEQ 1024
#define NB 4
#define NH 16
#define DK 128
#define DV 128
#define HID 2048
#define NQKVZ 8192
#define CONV_DIM 6144

static __device__ __forceinline__ float bf2f(u16 u) {
    union { u32 i; float f; } x; x.i = ((u32)u) << 16; return x.f;
}
static __device__ __forceinline__ u16 f2bf(float f) {
    union { float f; u32 u; } x; x.f = f;
    u32 r = x.u + 0x7FFF + ((x.u >> 16) & 1);
    return (u16)(r >> 16);
}

// ---------------- fp32 -> bf16 elementwise convert ---------------------------
__global__ __launch_bounds__(256) void f32_to_bf16(
    const float* __restrict__ in, u16* __restrict__ out) {
    long i = ((long)blockIdx.x * 256 + threadIdx.x) * 8;
    float4 a = *(const float4*)(in + i);
    float4 b = *(const float4*)(in + i + 4);
    u16 tmp[8];
    tmp[0] = f2bf(a.x); tmp[1] = f2bf(a.y); tmp[2] = f2bf(a.z); tmp[3] = f2bf(a.w);
    tmp[4] = f2bf(b.x); tmp[5] = f2bf(b.y); tmp[6] = f2bf(b.z); tmp[7] = f2bf(b.w);
    *(uint4*)(out + i) = *(const uint4*)tmp;
}

// ---------------- transpose fp32 (RxC) -> bf16 (CxR) -------------------------
__global__ __launch_bounds__(256) void transpose_f32_bf16(
    const float* __restrict__ in, u16* __restrict__ out, int R, int C) {
    __shared__ float tile[32][33];
    int bx = blockIdx.x, by = blockIdx.y;
    int c = threadIdx.x & 31;
    int r0 = threadIdx.x >> 5;
#pragma unroll
    for (int i = 0; i < 4; i++) {
        int r = r0 + i * 8;
        tile[r][c] = in[(long)(by * 32 + r) * C + bx * 32 + c];
    }
    __syncthreads();
#pragma unroll
    for (int i = 0; i < 4; i++) {
        int r = r0 + i * 8;
        out[(long)(bx * 32 + r) * R + by * 32 + c] = f2bf(tile[c][r]);
    }
}

// ---------------- transpose fp32 (RxC) -> fp32 (CxR) -------------------------
__global__ __launch_bounds__(256) void transpose_f32_f32(
    const float* __restrict__ in, float* __restrict__ out, int R, int C) {
    __shared__ float tile[32][33];
    int bx = blockIdx.x, by = blockIdx.y;
    int c = threadIdx.x & 31;
    int r0 = threadIdx.x >> 5;
#pragma unroll
    for (int i = 0; i < 4; i++) {
        int r = r0 + i * 8;
        tile[r][c] = in[(long)(by * 32 + r) * C + bx * 32 + c];
    }
    __syncthreads();
#pragma unroll
    for (int i = 0; i < 4; i++) {
        int r = r0 + i * 8;
        out[(long)(bx * 32 + r) * R + by * 32 + c] = tile[c][r];
    }
}

// ---------------- GEMM: C[M,N] = A[M,K] * BT[N,K]^T, bf16 in, OutT out -------
#define BM 128
#define BN 128
#define BKK 32
#define LDT 40  // padded LDS row stride (elements)

static __device__ __forceinline__ void store_out(u16* p, float v)  { *p = f2bf(v); }
static __device__ __forceinline__ void store_out(float* p, float v){ *p = v; }

template <typename OutT>
__global__ __launch_bounds__(256) void gemm_abT(
    const u16* __restrict__ A, const u16* __restrict__ BT,
    OutT* __restrict__ C, int M, int N, int K) {
    __shared__ u16 As[BM * LDT];
    __shared__ u16 Bs[BN * LDT];
    int t = threadIdx.x;
    int lane = t & 63;
    int w = t >> 6;
    int wm = (w & 1) * 64;
    int wn = (w >> 1) * 64;
    int l15 = lane & 15;
    int quad = lane >> 4;
    long blockM = (long)blockIdx.y * BM;
    long blockN = (long)blockIdx.x * BN;

    float4v acc[4][4];
#pragma unroll
    for (int i = 0; i < 4; i++)
#pragma unroll
        for (int j = 0; j < 4; j++) acc[i][j] = (float4v){0.f, 0.f, 0.f, 0.f};

    int ar0 = t >> 2, ac0 = (t & 3) * 8;
    int ar1 = (t + 256) >> 2, ac1 = ((t + 256) & 3) * 8;

    const u16* Ab = A + blockM * K;
    const u16* Bb = BT + blockN * K;

    for (int k0 = 0; k0 < K; k0 += BKK) {
        uint4 av0 = *(const uint4*)(Ab + (long)ar0 * K + k0 + ac0);
        uint4 av1 = *(const uint4*)(Ab + (long)ar1 * K + k0 + ac1);
        uint4 bv0 = *(const uint4*)(Bb + (long)ar0 * K + k0 + ac0);
        uint4 bv1 = *(const uint4*)(Bb + (long)ar1 * K + k0 + ac1);
        __syncthreads();  // previous iteration's LDS reads done
        *(uint2*)(As + ar0 * LDT + ac0)     = make_uint2(av0.x, av0.y);
        *(uint2*)(As + ar0 * LDT + ac0 + 4) = make_uint2(av0.z, av0.w);
        *(uint2*)(As + ar1 * LDT + ac1)     = make_uint2(av1.x, av1.y);
        *(uint2*)(As + ar1 * LDT + ac1 + 4) = make_uint2(av1.z, av1.w);
        *(uint2*)(Bs + ar0 * LDT + ac0)     = make_uint2(bv0.x, bv0.y);
        *(uint2*)(Bs + ar0 * LDT + ac0 + 4) = make_uint2(bv0.z, bv0.w);
        *(uint2*)(Bs + ar1 * LDT + ac1)     = make_uint2(bv1.x, bv1.y);
        *(uint2*)(Bs + ar1 * LDT + ac1 + 4) = make_uint2(bv1.z, bv1.w);
        __syncthreads();

        union { short8 v; uint2 u[2]; } fa[4], fb[4];
#pragma unroll
        for (int i = 0; i < 4; i++) {
            const u16* pa = As + (wm + i * 16 + l15) * LDT + quad * 8;
            fa[i].u[0] = *(const uint2*)pa;
            fa[i].u[1] = *(const uint2*)(pa + 4);
            const u16* pb = Bs + (wn + i * 16 + l15) * LDT + quad * 8;
            fb[i].u[0] = *(const uint2*)pb;
            fb[i].u[1] = *(const uint2*)(pb + 4);
        }
#pragma unroll
        for (int i = 0; i < 4; i++)
#pragma unroll
            for (int j = 0; j < 4; j++)
                acc[i][j] = __builtin_amdgcn_mfma_f32_16x16x32_bf16(
                    fa[i].v, fb[j].v, acc[i][j], 0, 0, 0);
    }

#pragma unroll
    for (int i = 0; i < 4; i++) {
        long mrow = blockM + wm + i * 16 + quad * 4;
#pragma unroll
        for (int j = 0; j < 4; j++) {
            long col = blockN + wn + j * 16 + l15;
#pragma unroll
            for (int r = 0; r < 4; r++) {
                store_out(&C[(mrow + r) * N + col], acc[i][j][r]);
            }
        }
    }
}

// ---------------- ba: g = -exp(A_log)*softplus(a+dt_bias), beta=sigmoid(b) ---
__global__ __launch_bounds__(64) void ba_kernel(
    const float* __restrict__ hs, const float* __restrict__ WbaT,
    const float* __restrict__ A_log, const float* __restrict__ dt_bias,
    float* __restrict__ gout, float* __restrict__ bout) {
    int bl = blockIdx.x;  // b*L + l
    int b = bl >> 10, l = bl & 1023;
    int t = threadIdx.x;
    __shared__ __align__(16) float hb[HID];
    const float* hrow = hs + (long)bl * HID;
#pragma unroll
    for (int i = 0; i < 8; i++) {
        int idx = (t + i * 64) * 4;
        *(float4*)(hb + idx) = *(const float4*)(hrow + idx);
    }
    __syncthreads();
    int n = t & 31, hf = t >> 5;
    const float* wrow = WbaT + (long)n * HID + hf * 1024;
    const float* hp = hb + hf * 1024;
    float acc = 0.f;
    for (int i = 0; i < 1024; i += 4) {
        float4 wv = *(const float4*)(wrow + i);
        float4 hv = *(const float4*)(hp + i);
        acc += wv.x * hv.x + wv.y * hv.y + wv.z * hv.z + wv.w * hv.w;
    }
    acc += __shfl_down(acc, 32);
    if (t < 32) {
        if (n < 16) {
            bout[((long)(b * NH + n)) * L_SEQ + l] = 1.f / (1.f + expf(-acc));
        } else {
            int h = n - 16;
            float x = acc + dt_bias[h];
            float sp = (x > 20.f) ? x : log1pf(expf(x));
            gout[((long)(b * NH + h)) * L_SEQ + l] = -expf(A_log[h]) * sp;
        }
    }
}

// ---------------- conv(KS=4 causal depthwise) + l2norm(q,k) + split v --------
__global__ __launch_bounds__(256) void conv_qkv(
    const u16* __restrict__ qkvz, const float* __restrict__ conv_w,
    const float* __restrict__ conv_b,
    float* __restrict__ qs, float* __restrict__ ks, float* __restrict__ vs) {
    int bl = blockIdx.x;  // b*L + l
    int b = bl >> 10, l = bl & 1023;
    int t = threadIdx.x;
    __shared__ float xb[CONV_DIM];
    __shared__ float red[32][9];
    __shared__ float rbuf[32];

    for (int c = t; c < CONV_DIM; c += 256) {
        float acc = conv_b[c];
        float w0 = conv_w[c * 4 + 0];
        float w1 = conv_w[c * 4 + 1];
        float w2 = conv_w[c * 4 + 2];
        float w3 = conv_w[c * 4 + 3];
        long rowbase = (long)(b * L_SEQ) * NQKVZ + c;
        if (l - 3 >= 0) acc += bf2f(qkvz[rowbase + (long)(l - 3) * NQKVZ]) * w0;
        if (l - 2 >= 0) acc += bf2f(qkvz[rowbase + (long)(l - 2) * NQKVZ]) * w1;
        if (l - 1 >= 0) acc += bf2f(qkvz[rowbase + (long)(l - 1) * NQKVZ]) * w2;
        acc += bf2f(qkvz[rowbase + (long)l * NQKVZ]) * w3;
        xb[c] = acc;
    }
    __syncthreads();
    {
        int grp = t >> 3;   // 0..31 (q heads 0..15, k heads 16..31)
        int j8 = t & 7;
        float s = 0.f;
#pragma unroll
        for (int i = 0; i < 16; i++) {
            float xv = xb[grp * 128 + j8 * 16 + i];
            s += xv * xv;
        }
        red[grp][j8] = s;
    }
    __syncthreads();
    if (t < 32) {
        float s = 0.f;
#pragma unroll
        for (int i = 0; i < 8; i++) s += red[t][i];
        rbuf[t] = rsqrtf(s + 1e-6f);
    }
    __syncthreads();
    for (int c = t; c < CONV_DIM; c += 256) {
        float xv = xb[c];
        if (c < 2048) {
            int h = c >> 7, d = c & 127;
            qs[(((long)(b * NH + h)) * L_SEQ + l) * DK + d] = xv * rbuf[h];
        } else if (c < 4096) {
            int c2 = c - 2048;
            int h = c2 >> 7, d = c2 & 127;
            ks[(((long)(b * NH + h)) * L_SEQ + l) * DK + d] = xv * rbuf[16 + h];
        } else {
            int c2 = c - 4096;
            int h = c2 >> 7, d = c2 & 127;
            vs[(((long)(b * NH + h)) * L_SEQ + l) * DV + d] = xv;
        }
    }
}

// ---------------- sequential gated delta scan, barrier-free ------------------
// grid: B*H*4 blocks, 256 threads. kg = t&7 (8 k-groups of 16), dl = t>>3
// (32 d per block). k-reduction via __shfl_xor over the 8 adjacent lanes.
// Next-step q/k/v/g/beta prefetched into registers to hide global latency.
__global__ __launch_bounds__(256) void gdn_scan(
    const float* __restrict__ q, const float* __restrict__ k,
    const float* __restrict__ v, const float* __restrict__ g,
    const float* __restrict__ beta, float* __restrict__ o) {
    int bid = blockIdx.x;
    int dc = bid & 3;
    int h = (bid >> 2) & 15;
    int b = bid >> 6;
    int t = threadIdx.x;
    int kg = t & 7;
    int dl = t >> 3;
    int d = dc * 32 + dl;

    const long bh = (long)(b * NH + h);
    const float* kp = k + bh * L_SEQ * DK + kg * 16;
    const float* qp = q + bh * L_SEQ * DK + kg * 16;
    const float* vp = v + bh * L_SEQ * DV + d;
    const float* gp = g + bh * L_SEQ;
    const float* bp = beta + bh * L_SEQ;
    const float scale = 0.08838834764831845f;  // 128^-0.5

    float S[16];
#pragma unroll
    for (int j = 0; j < 16; j++) S[j] = 0.f;

    float4 kv4[4], qv4[4];
    float vv, gv, bv;
#pragma unroll
    for (int i = 0; i < 4; i++) {
        kv4[i] = *(const float4*)(kp + i * 4);
        qv4[i] = *(const float4*)(qp + i * 4);
    }
    vv = vp[0]; gv = gp[0]; bv = bp[0];

    for (int ts = 0; ts < L_SEQ; ts++) {
        float kf[16], qf[16];
#pragma unroll
        for (int i = 0; i < 4; i++) {
            kf[i * 4 + 0] = kv4[i].x; kf[i * 4 + 1] = kv4[i].y;
            kf[i * 4 + 2] = kv4[i].z; kf[i * 4 + 3] = kv4[i].w;
            qf[i * 4 + 0] = qv4[i].x; qf[i * 4 + 1] = qv4[i].y;
            qf[i * 4 + 2] = qv4[i].z; qf[i * 4 + 3] = qv4[i].w;
        }
        float eg = expf(gv), bt = bv, vval = vv;
        if (ts + 1 < L_SEQ) {  // prefetch next step
            long row = (long)(ts + 1) * DK;
#pragma unroll
            for (int i = 0; i < 4; i++) {
                kv4[i] = *(const float4*)(kp + row + i * 4);
                qv4[i] = *(const float4*)(qp + row + i * 4);
            }
            vv = vp[(long)(ts + 1) * DV];
            gv = gp[ts + 1]; bv = bp[ts + 1];
        }
        float p = 0.f;
#pragma unroll
        for (int j = 0; j < 16; j++) {
            S[j] *= eg;
            p += kf[j] * S[j];
        }
        p += __shfl_xor(p, 1);
        p += __shfl_xor(p, 2);
        p += __shfl_xor(p, 4);
        float delta = (vval - p) * bt;
        float oo = 0.f;
#pragma unroll
        for (int j = 0; j < 16; j++) {
            S[j] += kf[j] * delta;
            oo += qf[j] * S[j];
        }
        oo += __shfl_xor(oo, 1);
        oo += __shfl_xor(oo, 2);
        oo += __shfl_xor(oo, 4);
        if (kg == 0) {
            o[(((long)(b * L_SEQ + ts)) * NH + h) * DV + d] = oo * scale;
        }
    }
}

// ---------------- gated RMS norm -> bf16 A2 ----------------------------------
__global__ __launch_bounds__(128) void gated_norm(
    const float* __restrict__ o, const u16* __restrict__ qkvz,
    const float* __restrict__ norm_w, u16* __restrict__ A2) {
    int bid = blockIdx.x;  // (b*L+l)*16 + h
    int t = threadIdx.x;   // 0..127
    float ov = o[(long)bid * 128 + t];
    float s = ov * ov;
#pragma unroll
    for (int off = 32; off > 0; off >>= 1) s += __shfl_down(s, off);
    __shared__ float ws2[2];
    if ((t & 63) == 0) ws2[t >> 6] = s;
    __syncthreads();
    float tot = ws2[0] + ws2[1];
    float rinv = rsqrtf(tot * (1.f / 128.f) + 1e-6f);
    int bl = bid >> 4, h = bid & 15;
    float z = bf2f(qkvz[(long)bl * NQKVZ + CONV_DIM + h * 128 + t]);
    float sig = 1.f / (1.f + expf(-z));
    float val = ov * rinv * norm_w[t] * sig;
    A2[(long)bl * 2048 + h * 128 + t] = f2bf(val);
}

// ---------------- host-side launcher -----------------------------------------
extern "C" void kernel_launch(void* const* d_in, const int* in_sizes, int n_in,
                              void* d_out, int out_size, void* d_ws, size_t ws_size,
                              hipStream_t stream) {
    const float* hs    = (const float*)d_in[0];  // (4,1024,2048)
    const float* Wqkvz = (const float*)d_in[1];  // (2048,8192)
    const float* Wba   = (const float*)d_in[2];  // (2048,32)
    const float* convw = (const float*)d_in[3];  // (6144,4)
    const float* convb = (const float*)d_in[4];  // (6144,)
    const float* A_log = (const float*)d_in[5];  // (16,)
    const float* dtb   = (const float*)d_in[6];  // (16,)
    const float* normw = (const float*)d_in[7];  // (128,)
    const float* Wout  = (const float*)d_in[8];  // (2048,2048)

    char* ws = (char*)d_ws;
    size_t off = 0;
    auto alloc = [&](size_t bytes) {
        size_t o = off;
        off = (off + bytes + 255) & ~(size_t)255;
        return o;
    };
    // region0: WqkvzT (bf16, 32MB) — dead after GEMM1, reused for os (fp32, 32MB)
    size_t r0 = alloc((size_t)NQKVZ * HID * 2);
    // region1: hs_bf16 (16MB) — dead after GEMM1, reused for A2 (bf16, 16MB)
    size_t r1 = alloc((size_t)4096 * HID * 2);
    u16*   WqkvzT = (u16*)(ws + r0);
    float* os     = (float*)(ws + r0);
    u16*   hsb    = (u16*)(ws + r1);
    u16*   A2     = (u16*)(ws + r1);
    u16*   qkvz   = (u16*)(ws + alloc((size_t)4096 * NQKVZ * 2));
    float* qs     = (float*)(ws + alloc((size_t)4096 * 2048 * 4));
    float* ks     = (float*)(ws + alloc((size_t)4096 * 2048 * 4));
    float* vs     = (float*)(ws + alloc((size_t)4096 * 2048 * 4));
    float* gs     = (float*)(ws + alloc((size_t)NB * NH * L_SEQ * 4));
    float* bs     = (float*)(ws + alloc((size_t)NB * NH * L_SEQ * 4));
    u16*   WoutT  = (u16*)(ws + alloc((size_t)HID * 2048 * 2));
    float* WbaT   = (float*)(ws + alloc((size_t)32 * HID * 4));

    // 1. convert + transposes (fp32 -> bf16 weights/activations)
    hipLaunchKernelGGL(f32_to_bf16, dim3(4096), dim3(256), 0, stream, hs, hsb);
    hipLaunchKernelGGL(transpose_f32_bf16, dim3(NQKVZ / 32, HID / 32), dim3(256), 0, stream,
                       Wqkvz, WqkvzT, HID, NQKVZ);
    hipLaunchKernelGGL(transpose_f32_bf16, dim3(2048 / 32, 2048 / 32), dim3(256), 0, stream,
                       Wout, WoutT, 2048, 2048);
    hipLaunchKernelGGL(transpose_f32_f32, dim3(1, HID / 32), dim3(256), 0, stream,
                       Wba, WbaT, HID, 32);

    // 2. big GEMM: qkvz = hs @ W_qkvz (bf16 in, bf16 out)
    hipLaunchKernelGGL((gemm_abT<u16>), dim3(NQKVZ / BN, 4096 / BM), dim3(256), 0, stream,
                       hsb, WqkvzT, qkvz, 4096, NQKVZ, HID);

    // 3. ba -> g, beta (pure fp32)
    hipLaunchKernelGGL(ba_kernel, dim3(4096), dim3(64), 0, stream,
                       hs, WbaT, A_log, dtb, gs, bs);

    // 4. conv + l2norm -> q,k,v (fp32)
    hipLaunchKernelGGL(conv_qkv, dim3(4096), dim3(256), 0, stream,
                       qkvz, convw, convb, qs, ks, vs);

    // 5. scan (fp32, barrier-free)
    hipLaunchKernelGGL(gdn_scan, dim3(NB * NH * 4), dim3(256), 0, stream,
                       qs, ks, vs, gs, bs, os);

    // 6. gated RMS norm -> bf16 A2
    hipLaunchKernelGGL(gated_norm, dim3(4096 * NH), dim3(128), 0, stream,
                       os, qkvz, normw, A2);

    // 7. out = A2 @ W_out (bf16 in, fp32 out)
    hipLaunchKernelGGL((gemm_abT<float>), dim3(2048 / BN, 4096 / BM), dim3(256), 0, stream,
                       A2, WoutT, (float*)d_out, 4096, 2048, HID);
}